// Round 1
// baseline (788.880 us; speedup 1.0000x reference)
//
#include <hip/hip_runtime.h>
#include <cstdint>
#include <cmath>

#define HH 512
#define WW 512
#define NB 8
#define NC 11
#define NPIX (HH*WW)

// ---------------- Stage A: fused onehot+blur+sobel+nms+threshold ----------------
#define TA 64
#define GTD 72      // gt tile dim (tile + 4 halo each side)
#define BD 68       // blurred region dim (tile + 2 each side)
#define T1C 72      // vertical-blur intermediate cols
#define MD 66       // mag region dim (tile + 1 each side)

__device__ __forceinline__ int reflect512(int t) {
  t = t < 0 ? -t : t;
  return t > 511 ? 1022 - t : t;
}

__global__ __launch_bounds__(256) void k_edges(const int* __restrict__ gt,
                                               uint8_t* __restrict__ state) {
  __shared__ uint8_t sgt[GTD*GTD];
  __shared__ float sb[BD*BD];
  __shared__ float su[BD*T1C];   // union: t1 (68x72) then mag (66x66)

  const int r0 = blockIdx.y * TA, c0 = blockIdx.x * TA;
  const int bimg = blockIdx.z;
  const int tid = threadIdx.x;
  const int* gtb = gt + bimg * NPIX;

  for (int i = tid; i < GTD*GTD; i += 256) {
    int lr = i / GTD, lc = i - lr*GTD;
    int gr = reflect512(r0 + lr - 4);
    int gc = reflect512(c0 + lc - 4);
    sgt[i] = (uint8_t)gtb[gr*WW + gc];
  }
  __syncthreads();

  const float g0 = 0.054488684549642945f;
  const float g1 = 0.24420134200323332f;
  const float g2 = 0.4026199468942475f;

  for (int c = 0; c < NC; ++c) {
    // vertical blur: t1[lb][lxc], lb row -> global row r0+lb-2, lxc col -> global col c0+lxc-4
    float* t1 = su;
    for (int i = tid; i < BD*T1C; i += 256) {
      int lb = i / T1C, lxc = i - lb*T1C;
      const uint8_t* col = &sgt[lb*GTD + lxc];
      t1[i] = g0*((col[0]==c)?1.f:0.f)
            + g1*((col[GTD]==c)?1.f:0.f)
            + g2*((col[2*GTD]==c)?1.f:0.f)
            + g1*((col[3*GTD]==c)?1.f:0.f)
            + g0*((col[4*GTD]==c)?1.f:0.f);
    }
    __syncthreads();
    // horizontal blur: sb[lb][lbc] -> global (r0+lb-2, c0+lbc-2)
    for (int i = tid; i < BD*BD; i += 256) {
      int lb = i / BD, lbc = i - lb*BD;
      const float* row = &t1[lb*T1C + lbc];
      sb[i] = g0*row[0] + g1*row[1] + g2*row[2] + g1*row[3] + g0*row[4];
    }
    __syncthreads();

    // b accessor with edge-clamp (Sobel pad mode 'edge')
    auto BLD = [&](int y, int x) -> float {
      y = y < 0 ? 0 : (y > 511 ? 511 : y);
      x = x < 0 ? 0 : (x > 511 ? 511 : x);
      return sb[(y - r0 + 2)*BD + (x - c0 + 2)];
    };

    // mag into su (aliases t1; t1 dead after sb)
    float* mg = su;
    for (int i = tid; i < MD*MD; i += 256) {
      int lm = i / MD, lmc = i - lm*MD;
      int gm = r0 + lm - 1, gmc = c0 + lmc - 1;
      if (gm >= 0 && gm < HH && gmc >= 0 && gmc < WW) {
        float bmm = BLD(gm-1,gmc-1), bm0 = BLD(gm-1,gmc), bmp = BLD(gm-1,gmc+1);
        float b0m = BLD(gm,  gmc-1),                       b0p = BLD(gm,  gmc+1);
        float bpm = BLD(gm+1,gmc-1), bp0 = BLD(gm+1,gmc), bpp = BLD(gm+1,gmc+1);
        float gx = (bmp + 2.f*b0p + bpp) - (bmm + 2.f*b0m + bpm);
        float gy = (bpm + 2.f*bp0 + bpp) - (bmm + 2.f*bm0 + bmp);
        mg[lm*MD + lmc] = sqrtf(gx*gx + gy*gy + 1e-6f);
      }
    }
    __syncthreads();

    // output: NMS + double threshold
    for (int i = tid; i < TA*TA; i += 256) {
      int lr = i / TA, lc = i - lr*TA;
      int gi = r0 + lr, gj = c0 + lc;
      float bmm = BLD(gi-1,gj-1), bm0 = BLD(gi-1,gj), bmp = BLD(gi-1,gj+1);
      float b0m = BLD(gi,  gj-1),                      b0p = BLD(gi,  gj+1);
      float bpm = BLD(gi+1,gj-1), bp0 = BLD(gi+1,gj), bpp = BLD(gi+1,gj+1);
      float gx = (bmp + 2.f*b0p + bpp) - (bmm + 2.f*b0m + bpm);
      float gy = (bpm + 2.f*bp0 + bpp) - (bmm + 2.f*bm0 + bmp);
      float ang_f = atan2f(gy, gx) * (float)(180.0 / M_PI);
      int ang = (int)rintf(ang_f / 45.0f);
      int pos = ((ang % 8) + 8) % 8;
      int neg = (pos + 4) & 7;
      float m = mg[(lr+1)*MD + (lc+1)];
      // packed (d+1) tables: dr: [1,0,0,0,1,2,2,2] -> 0xA901 ; dc: [2,2,1,0,0,0,1,2] -> 0x901A
      int drp = ((0xA901 >> (2*pos)) & 3) - 1;
      int dcp = ((0x901A >> (2*pos)) & 3) - 1;
      int drn = ((0xA901 >> (2*neg)) & 3) - 1;
      int dcn = ((0x901A >> (2*neg)) & 3) - 1;
      int pr = gi + drp, pc = gj + dcp;
      int nr = gi + drn, nc2 = gj + dcn;
      float cp = m - ((pr>=0 && pr<HH && pc>=0 && pc<WW) ? mg[(pr-r0+1)*MD + (pc-c0+1)] : 0.f);
      float cn = m - ((nr>=0 && nr<HH && nc2>=0 && nc2<WW) ? mg[(nr-r0+1)*MD + (nc2-c0+1)] : 0.f);
      uint8_t st = 0;
      if (cp > 0.f && cn > 0.f) {
        if (m > 0.2f) st = 2;
        else if (m > 0.1f) st = 1;
      }
      state[(size_t)(bimg*NC + c)*NPIX + (size_t)gi*WW + gj] = st;
    }
    __syncthreads();
  }
}

// ---------------- Stage B: hysteresis propagation ----------------
#define HR 128
#define HC 256
#define HLW (HC + 2)

__global__ __launch_bounds__(256) void k_hyst(uint8_t* __restrict__ state) {
  __shared__ uint8_t st[(HR+2)*HLW];
  __shared__ int flag;
  const int img = blockIdx.z;
  const int r0 = blockIdx.y * HR, c0 = blockIdx.x * HC;
  uint8_t* sg = state + (size_t)img * NPIX;
  const int tid = threadIdx.x;

  for (int i = tid; i < (HR+2)*HLW; i += 256) {
    int lr = i / HLW, lc = i - lr*HLW;
    int gr = r0 + lr - 1, gc = c0 + lc - 1;
    st[i] = (gr >= 0 && gr < HH && gc >= 0 && gc < WW) ? sg[gr*WW + gc] : (uint8_t)0;
  }
  __syncthreads();

  for (int it = 0; it < 600; ++it) {
    if (tid == 0) flag = 0;
    __syncthreads();
    int ch = 0;
    #pragma unroll 4
    for (int k = 0; k < (HR*HC)/256; ++k) {
      int ci = tid + k*256;
      int r = (ci >> 8) + 1, c = (ci & 255) + 1;
      int idx = r*HLW + c;
      if (st[idx] == 1) {
        int s = st[idx-HLW-1] | st[idx-HLW] | st[idx-HLW+1]
              | st[idx-1]     | st[idx+1]
              | st[idx+HLW-1] | st[idx+HLW] | st[idx+HLW+1];
        if (s & 2) { st[idx] = 2; ch = 1; }
      }
    }
    if (ch) flag = 1;
    __syncthreads();
    if (!flag) break;
  }

  for (int k = 0; k < (HR*HC)/256; ++k) {
    int ci = tid + k*256;
    int r = ci >> 8, c = ci & 255;
    sg[(r0 + r)*WW + c0 + c] = st[(r+1)*HLW + (c+1)];
  }
}

// ---------------- Stage C: loss reduction ----------------
__global__ __launch_bounds__(256) void k_loss(const float* __restrict__ pd,
                                              const int* __restrict__ gt,
                                              const float* __restrict__ wt,
                                              const uint8_t* __restrict__ state,
                                              double* __restrict__ acc) {
  int pix = blockIdx.x * 256 + threadIdx.x;
  float contrib = 0.f;
  if (pix < NB*NPIX) {
    int b = pix / NPIX, p = pix - b*NPIX;
    int h = p / WW, w = p - h*WW;
    int g = gt[pix];
    const float* pb = pd + (size_t)b * NC * NPIX + p;
    // online logsumexp over channels
    float m = -3.4e38f, s = 0.f, vg = 0.f;
    #pragma unroll
    for (int c = 0; c < NC; ++c) {
      float x = pb[(size_t)c * NPIX];
      if (c == g) vg = x;
      float mn = fmaxf(m, x);
      s = s * expf(m - mn) + expf(x - mn);
      m = mn;
    }
    float lse = m + logf(s);
    const uint8_t* sgc = state + (size_t)(b*NC + g) * NPIX;
    int e = (sgc[p] == 2);
    if (h > 0)      e |= (sgc[p - WW] == 2);
    if (h < HH-1)   e |= (sgc[p + WW] == 2);
    if (w > 0)      e |= (sgc[p - 1]  == 2);
    if (w < WW-1)   e |= (sgc[p + 1]  == 2);
    contrib = wt[g] * (vg - lse) * (1.f + 2.f * (float)e);
  }
  // wave + block reduce
  float s2 = contrib;
  #pragma unroll
  for (int o = 32; o > 0; o >>= 1) s2 += __shfl_down(s2, o, 64);
  __shared__ float wsum[4];
  if ((threadIdx.x & 63) == 0) wsum[threadIdx.x >> 6] = s2;
  __syncthreads();
  if (threadIdx.x == 0) {
    double d = (double)wsum[0] + (double)wsum[1] + (double)wsum[2] + (double)wsum[3];
    atomicAdd(acc, d);
  }
}

__global__ void k_fin(const double* __restrict__ acc, float* __restrict__ out) {
  if (threadIdx.x == 0 && blockIdx.x == 0)
    out[0] = (float)(-acc[0] / 2097152.0);
}

extern "C" void kernel_launch(void* const* d_in, const int* in_sizes, int n_in,
                              void* d_out, int out_size, void* d_ws, size_t ws_size,
                              hipStream_t stream) {
  const float* pd = (const float*)d_in[0];
  const int*   gt = (const int*)d_in[1];
  const float* wt = (const float*)d_in[2];
  float* out = (float*)d_out;
  double* acc = (double*)d_ws;
  uint8_t* state = (uint8_t*)d_ws + 256;

  hipMemsetAsync(d_ws, 0, 256, stream);

  dim3 gA(WW/TA, HH/TA, NB);           // 8 x 8 x 8
  k_edges<<<gA, 256, 0, stream>>>(gt, state);

  dim3 gH(WW/HC, HH/HR, NB*NC);        // 2 x 4 x 88
  for (int i = 0; i < 8; ++i)
    k_hyst<<<gH, 256, 0, stream>>>(state);

  k_loss<<<(NB*NPIX)/256, 256, 0, stream>>>(pd, gt, wt, state, acc);
  k_fin<<<1, 64, 0, stream>>>(acc, out);
}

// Round 2
// 235.365 us; speedup vs baseline: 3.3517x; 3.3517x over previous
//
#include <hip/hip_runtime.h>
#include <cstdint>
#include <cmath>

#define HH 512
#define WW 512
#define NB 8
#define NC 11
#define NPIX (HH*WW)
#define NWPR 8                 // 512/64 words per row
#define NWORDS (HH*NWPR)       // 4096 words per image-channel

typedef unsigned long long u64;

__device__ __forceinline__ int reflect512(int t) {
  t = t < 0 ? -t : t;
  return t > 511 ? 1022 - t : t;
}

// ---------------- Stage A: onehot+blur+sobel+nms+threshold -> bitmasks ----------------
#define TA 64
#define GTD 72      // gt tile dim (tile + 4 halo)
#define BD 68       // blurred region dim (tile + 2 halo)
#define T1C 72      // vertical-blur intermediate cols
#define MD 66       // mag region dim (tile + 1 halo)

__global__ __launch_bounds__(256) void k_edges(const int* __restrict__ gt,
                                               u64* __restrict__ strongw,
                                               u64* __restrict__ weakw) {
  __shared__ uint8_t smask[GTD*GTD];
  __shared__ float sb[BD*BD];
  __shared__ float su[BD*T1C];   // union: t1 (68x72), then mag (66x66)
  __shared__ uint8_t sax[TA*TA];

  const int z = blockIdx.z;          // bimg*NC + c
  const int bimg = z / NC;
  const int c = z - bimg*NC;
  const int r0 = blockIdx.y * TA, c0 = blockIdx.x * TA;
  const int tid = threadIdx.x;
  const int* gtb = gt + bimg * NPIX;

  for (int i = tid; i < GTD*GTD; i += 256) {
    int lr = i / GTD, lc = i - lr*GTD;
    smask[i] = (gtb[reflect512(r0 + lr - 4)*WW + reflect512(c0 + lc - 4)] == c) ? 1 : 0;
  }
  __syncthreads();

  const float g0 = 0.054488684549642945f;
  const float g1 = 0.24420134200323332f;
  const float g2 = 0.4026199468942475f;

  // vertical blur, 4 outputs/thread via u32 mask reads
  float* t1 = su;
  for (int q = tid; q < 68*18; q += 256) {
    int lb = q / 18, lcq = q - lb*18;
    const uint8_t* base = &smask[lb*GTD + lcq*4];
    uint32_t w0 = *(const uint32_t*)(base);
    uint32_t w1 = *(const uint32_t*)(base + GTD);
    uint32_t w2 = *(const uint32_t*)(base + 2*GTD);
    uint32_t w3 = *(const uint32_t*)(base + 3*GTD);
    uint32_t w4 = *(const uint32_t*)(base + 4*GTD);
    float4 o;
    float* op = &o.x;
    #pragma unroll
    for (int j = 0; j < 4; ++j) {
      int s04 = (int)((w0 >> (8*j)) & 1u) + (int)((w4 >> (8*j)) & 1u);
      int s13 = (int)((w1 >> (8*j)) & 1u) + (int)((w3 >> (8*j)) & 1u);
      int s2  = (int)((w2 >> (8*j)) & 1u);
      op[j] = g0*(float)s04 + g1*(float)s13 + g2*(float)s2;
    }
    *(float4*)&t1[lb*T1C + lcq*4] = o;
  }
  __syncthreads();

  // horizontal blur, 4 outputs/thread via float4 reads
  for (int q = tid; q < 68*17; q += 256) {
    int lb = q / 17, lcq = q - lb*17;
    const float* rp = &t1[lb*T1C + lcq*4];
    float4 a = *(const float4*)rp;
    float4 b = *(const float4*)(rp + 4);
    float4 o;
    o.x = g0*(a.x + b.x) + g1*(a.y + a.w) + g2*a.z;
    o.y = g0*(a.y + b.y) + g1*(a.z + b.x) + g2*a.w;
    o.z = g0*(a.z + b.z) + g1*(a.w + b.y) + g2*b.x;
    o.w = g0*(a.w + b.w) + g1*(b.x + b.z) + g2*b.y;
    *(float4*)&sb[lb*BD + lcq*4] = o;
  }
  __syncthreads();

  // bake the Sobel edge-clamp into sb: duplicate border rows/cols (border blocks only)
  if (r0 == 0)      for (int i = tid; i < 2*BD; i += 256) { int rr = i/BD, cc = i - (i/BD)*BD; sb[rr*BD + cc] = sb[2*BD + cc]; }
  if (r0 == HH-TA)  for (int i = tid; i < 2*BD; i += 256) { int rr = 66 + i/BD, cc = i % BD;  sb[rr*BD + cc] = sb[65*BD + cc]; }
  __syncthreads();
  if (c0 == 0)      for (int i = tid; i < 2*BD; i += 256) { int rr = i >> 1, cc = i & 1;       sb[rr*BD + cc] = sb[rr*BD + 2]; }
  if (c0 == WW-TA)  for (int i = tid; i < 2*BD; i += 256) { int rr = i >> 1, cc = 66 + (i & 1); sb[rr*BD + cc] = sb[rr*BD + 65]; }
  __syncthreads();

  // sobel -> mag (zero-padded at image border, matches NMS 'SAME') + axis for central pixels
  float* mg = su;   // t1 dead
  for (int i = tid; i < MD*MD; i += 256) {
    int lm = i / MD, lmc = i - lm*MD;
    int gm = r0 + lm - 1, gmc = c0 + lmc - 1;
    float mval = 0.f;
    if (gm >= 0 && gm < HH && gmc >= 0 && gmc < WW) {
      const float* s0 = &sb[lm*BD + lmc];
      float bmm = s0[0],    bm0 = s0[1],      bmp = s0[2];
      float b0m = s0[BD],                     b0p = s0[BD+2];
      float bpm = s0[2*BD], bp0 = s0[2*BD+1], bpp = s0[2*BD+2];
      float gx = (bmp + 2.f*b0p + bpp) - (bmm + 2.f*b0m + bpm);
      float gy = (bpm + 2.f*bp0 + bpp) - (bmm + 2.f*bm0 + bmp);
      mval = sqrtf(gx*gx + gy*gy + 1e-6f);
      if ((unsigned)(lm-1) < 64u && (unsigned)(lmc-1) < 64u) {
        float ax = fabsf(gx), ay = fabsf(gy);
        int axis;
        if (ay <= 0.41421356237f*ax) axis = 0;          // horizontal axis
        else if (ay >= 2.41421356237f*ax) axis = 2;     // vertical axis
        else axis = (gx*gy > 0.f) ? 1 : 3;              // diagonals
        sax[(lm-1)*TA + (lmc-1)] = (uint8_t)axis;
      }
    }
    mg[i] = mval;
  }
  __syncthreads();

  // NMS + double threshold -> ballot-packed bit words
  const int lane = tid & 63;
  const int wv = tid >> 6;
  size_t obase = (size_t)z * NWORDS + (size_t)r0*NWPR + (size_t)(c0 >> 6);
  for (int k = 0; k < 16; ++k) {
    int lr = wv + k*4;
    float m = mg[(lr+1)*MD + (lane+1)];
    int a = sax[lr*TA + lane];
    int dr = ((0x01 >> (2*a)) & 3) - 1;   // {0,-1,-1,-1}
    int dc = ((0x1A >> (2*a)) & 3) - 1;   // {1, 1, 0,-1}
    float m1 = mg[(lr+1+dr)*MD + (lane+1+dc)];
    float m2 = mg[(lr+1-dr)*MD + (lane+1-dc)];
    bool pass = (m - m1 > 0.f) && (m - m2 > 0.f);
    u64 sw = __ballot(pass && m > 0.2f);
    u64 wk = __ballot(pass && m > 0.1f);
    if (lane == 0) {
      strongw[obase + (size_t)lr*NWPR] = sw;
      weakw  [obase + (size_t)lr*NWPR] = wk;
    }
  }
}

// ---------------- Stage B: bit-packed hysteresis to global fixpoint + cross-dilate ----------------
#define HT 512
__global__ __launch_bounds__(HT) void k_hyst(const u64* __restrict__ strongw,
                                             const u64* __restrict__ weakw,
                                             u64* __restrict__ dil) {
  __shared__ u64 S[NWORDS];
  __shared__ int flag;
  const int z = blockIdx.x;
  const u64* sg = strongw + (size_t)z * NWORDS;
  const u64* wg = weakw   + (size_t)z * NWORDS;
  u64* dg = dil + (size_t)z * NWORDS;
  const int tid = threadIdx.x;

  for (int i = tid; i < NWORDS; i += HT) S[i] = sg[i];
  u64 wk[8];
  #pragma unroll
  for (int cw = 0; cw < 8; ++cw) wk[cw] = wg[tid*8 + cw];
  __syncthreads();

  const int r = tid;   // one row per thread
  for (int iter = 0; iter < 4000; ++iter) {
    if (tid == 0) flag = 0;
    __syncthreads();
    int changed = 0;
    u64 md[8], v[8];
    #pragma unroll
    for (int cw = 0; cw < 8; ++cw) md[cw] = S[r*8 + cw];
    #pragma unroll
    for (int cw = 0; cw < 8; ++cw) {
      u64 up = (r > 0)   ? S[(r-1)*8 + cw] : 0ull;
      u64 dn = (r < 511) ? S[(r+1)*8 + cw] : 0ull;
      v[cw] = up | md[cw] | dn;
    }
    #pragma unroll
    for (int cw = 0; cw < 8; ++cw) {
      u64 vp = (cw > 0) ? v[cw-1] : 0ull;
      u64 vn = (cw < 7) ? v[cw+1] : 0ull;
      u64 D = (v[cw] << 1) | v[cw] | (v[cw] >> 1) | (vp >> 63) | (vn << 63);
      u64 nw = md[cw] | (wk[cw] & D);
      if (nw != md[cw]) { S[r*8 + cw] = nw; changed = 1; }
    }
    if (changed) flag = 1;
    __syncthreads();
    if (!flag) break;
  }

  // cross-dilate (up,down,left,right,center) and write out
  for (int i = tid; i < NWORDS; i += HT) {
    int rr = i >> 3, cw = i & 7;
    u64 s = S[i];
    u64 d = s | (s << 1) | (s >> 1);
    if (cw > 0)   d |= S[i-1] >> 63;
    if (cw < 7)   d |= S[i+1] << 63;
    if (rr > 0)   d |= S[i-8];
    if (rr < 511) d |= S[i+8];
    dg[i] = d;
  }
}

// ---------------- Stage C: loss reduction ----------------
__global__ __launch_bounds__(256) void k_loss(const float* __restrict__ pd,
                                              const int* __restrict__ gt,
                                              const float* __restrict__ wt,
                                              const u64* __restrict__ dil,
                                              double* __restrict__ acc) {
  int pix = blockIdx.x * 256 + threadIdx.x;
  float contrib = 0.f;
  if (pix < NB*NPIX) {
    int b = pix / NPIX, p = pix - b*NPIX;
    int g = gt[pix];
    const float* pb = pd + (size_t)b * NC * NPIX + p;
    float m = -3.4e38f, s = 0.f, vg = 0.f;
    #pragma unroll
    for (int c = 0; c < NC; ++c) {
      float x = pb[(size_t)c * NPIX];
      if (c == g) vg = x;
      float mn = fmaxf(m, x);
      s = s * expf(m - mn) + expf(x - mn);
      m = mn;
    }
    float lse = m + logf(s);
    u64 w = dil[(size_t)(b*NC + g) * NWORDS + (p >> 6)];
    int e = (int)((w >> (p & 63)) & 1ull);
    contrib = wt[g] * (vg - lse) * (1.f + 2.f*(float)e);
  }
  float s2 = contrib;
  #pragma unroll
  for (int o = 32; o > 0; o >>= 1) s2 += __shfl_down(s2, o, 64);
  __shared__ float wsum[4];
  if ((threadIdx.x & 63) == 0) wsum[threadIdx.x >> 6] = s2;
  __syncthreads();
  if (threadIdx.x == 0) {
    double d = (double)wsum[0] + (double)wsum[1] + (double)wsum[2] + (double)wsum[3];
    atomicAdd(acc, d);
  }
}

__global__ void k_fin(const double* __restrict__ acc, float* __restrict__ out) {
  if (threadIdx.x == 0 && blockIdx.x == 0)
    out[0] = (float)(-acc[0] / 2097152.0);
}

extern "C" void kernel_launch(void* const* d_in, const int* in_sizes, int n_in,
                              void* d_out, int out_size, void* d_ws, size_t ws_size,
                              hipStream_t stream) {
  const float* pd = (const float*)d_in[0];
  const int*   gt = (const int*)d_in[1];
  const float* wt = (const float*)d_in[2];
  float* out = (float*)d_out;

  double* acc = (double*)d_ws;
  u64* strongw = (u64*)((char*)d_ws + 256);
  u64* weakw   = strongw + (size_t)NB*NC*NWORDS;
  u64* dilw    = weakw   + (size_t)NB*NC*NWORDS;

  hipMemsetAsync(d_ws, 0, 256, stream);

  dim3 gA(WW/TA, HH/TA, NB*NC);        // 8 x 8 x 88
  k_edges<<<gA, 256, 0, stream>>>(gt, strongw, weakw);

  k_hyst<<<NB*NC, HT, 0, stream>>>(strongw, weakw, dilw);

  k_loss<<<(NB*NPIX)/256, 256, 0, stream>>>(pd, gt, wt, dilw, acc);
  k_fin<<<1, 64, 0, stream>>>(acc, out);
}

// Round 4
// 148.772 us; speedup vs baseline: 5.3026x; 1.5821x over previous
//
#include <hip/hip_runtime.h>
#include <cstdint>
#include <cmath>

#define HH 512
#define WW 512
#define NB 8
#define NC 11
#define NPIX (HH*WW)
#define NWPR 8                 // 512/64 words per row
#define NWORDS (HH*NWPR)       // 4096 words per image-channel

typedef unsigned long long u64;

__device__ __forceinline__ int reflect512(int t) {
  t = t < 0 ? -t : t;
  return t > 511 ? 1022 - t : t;
}

// ---------------- Stage A: onehot+blur+sobel+nms+threshold -> bitmasks ----------------
#define TA 64
#define GTD 72      // gt tile dim (tile + 4 halo)
#define BD 68       // blurred region dim (tile + 2 halo)
#define T1C 72      // vertical-blur intermediate cols
#define MD 66       // mag region dim (tile + 1 halo)

__global__ __launch_bounds__(256) void k_edges(const int* __restrict__ gt,
                                               u64* __restrict__ strongw,
                                               u64* __restrict__ weakw) {
  __shared__ uint8_t smask[GTD*GTD];
  __shared__ float sb[BD*BD];
  __shared__ float su[BD*T1C];   // union: t1 (68x72), then mag^2 (66x66)
  __shared__ uint8_t sax[TA*TA];

  const int z = blockIdx.z;          // bimg*NC + c
  const int bimg = z / NC;
  const int c = z - bimg*NC;
  const int r0 = blockIdx.y * TA, c0 = blockIdx.x * TA;
  const int tid = threadIdx.x;
  const int* gtb = gt + bimg * NPIX;

  for (int i = tid; i < GTD*GTD; i += 256) {
    int lr = i / GTD, lc = i - lr*GTD;
    smask[i] = (gtb[reflect512(r0 + lr - 4)*WW + reflect512(c0 + lc - 4)] == c) ? 1 : 0;
  }
  __syncthreads();

  const float g0 = 0.054488684549642945f;
  const float g1 = 0.24420134200323332f;
  const float g2 = 0.4026199468942475f;

  // vertical blur, 4 outputs/thread; packed-byte adds (values <=2, no carry)
  float* t1 = su;
  for (int q = tid; q < 68*18; q += 256) {
    int lb = q / 18, lcq = q - lb*18;
    const uint8_t* base = &smask[lb*GTD + lcq*4];
    uint32_t w0 = *(const uint32_t*)(base);
    uint32_t w1 = *(const uint32_t*)(base + GTD);
    uint32_t w2 = *(const uint32_t*)(base + 2*GTD);
    uint32_t w3 = *(const uint32_t*)(base + 3*GTD);
    uint32_t w4 = *(const uint32_t*)(base + 4*GTD);
    uint32_t s04 = w0 + w4;   // per-byte sums, max 2
    uint32_t s13 = w1 + w3;
    float4 o;
    float* op = &o.x;
    #pragma unroll
    for (int j = 0; j < 4; ++j) {
      float a  = (float)((s04 >> (8*j)) & 0xffu);
      float bb = (float)((s13 >> (8*j)) & 0xffu);
      float d  = (float)((w2  >> (8*j)) & 0xffu);
      op[j] = g0*a + g1*bb + g2*d;
    }
    *(float4*)&t1[lb*T1C + lcq*4] = o;
  }
  __syncthreads();

  // horizontal blur, 4 outputs/thread via float4 reads
  for (int q = tid; q < 68*17; q += 256) {
    int lb = q / 17, lcq = q - lb*17;
    const float* rp = &t1[lb*T1C + lcq*4];
    float4 a = *(const float4*)rp;
    float4 b = *(const float4*)(rp + 4);
    float4 o;
    o.x = g0*(a.x + b.x) + g1*(a.y + a.w) + g2*a.z;
    o.y = g0*(a.y + b.y) + g1*(a.z + b.x) + g2*a.w;
    o.z = g0*(a.z + b.z) + g1*(a.w + b.y) + g2*b.x;
    o.w = g0*(a.w + b.w) + g1*(b.x + b.z) + g2*b.y;
    *(float4*)&sb[lb*BD + lcq*4] = o;
  }
  __syncthreads();

  // bake the Sobel edge-clamp into sb: duplicate border rows/cols (border blocks only)
  if (r0 == 0)      for (int i = tid; i < 2*BD; i += 256) { int rr = i/BD, cc = i - (i/BD)*BD; sb[rr*BD + cc] = sb[2*BD + cc]; }
  if (r0 == HH-TA)  for (int i = tid; i < 2*BD; i += 256) { int rr = 66 + i/BD, cc = i % BD;  sb[rr*BD + cc] = sb[65*BD + cc]; }
  __syncthreads();
  if (c0 == 0)      for (int i = tid; i < 2*BD; i += 256) { int rr = i >> 1, cc = i & 1;       sb[rr*BD + cc] = sb[rr*BD + 2]; }
  if (c0 == WW-TA)  for (int i = tid; i < 2*BD; i += 256) { int rr = i >> 1, cc = 66 + (i & 1); sb[rr*BD + cc] = sb[rr*BD + 65]; }
  __syncthreads();

  // sobel -> mag^2 (no sqrt; eps cancels in all comparisons) + axis for central pixels
  float* mg = su;   // t1 dead
  for (int i = tid; i < MD*MD; i += 256) {
    int lm = i / MD, lmc = i - lm*MD;
    int gm = r0 + lm - 1, gmc = c0 + lmc - 1;
    float mval = 0.f;
    if (gm >= 0 && gm < HH && gmc >= 0 && gmc < WW) {
      const float* s0 = &sb[lm*BD + lmc];
      float bmm = s0[0],    bm0 = s0[1],      bmp = s0[2];
      float b0m = s0[BD],                     b0p = s0[BD+2];
      float bpm = s0[2*BD], bp0 = s0[2*BD+1], bpp = s0[2*BD+2];
      float gx = (bmp + 2.f*b0p + bpp) - (bmm + 2.f*b0m + bpm);
      float gy = (bpm + 2.f*bp0 + bpp) - (bmm + 2.f*bm0 + bmp);
      float gx2 = gx*gx, gy2 = gy*gy;
      mval = gx2 + gy2;
      if ((unsigned)(lm-1) < 64u && (unsigned)(lmc-1) < 64u) {
        int axis;
        if (gy2 <= 0.17157287525f*gx2) axis = 0;          // |gy| <= tan(22.5)|gx|
        else if (gy2 >= 5.82842712475f*gx2) axis = 2;     // |gy| >= tan(67.5)|gx|
        else axis = (gx*gy > 0.f) ? 1 : 3;                // diagonals
        sax[(lm-1)*TA + (lmc-1)] = (uint8_t)axis;
      }
    }
    mg[i] = mval;
  }
  __syncthreads();

  // NMS + double threshold (on squares) -> ballot-packed bit words
  const int lane = tid & 63;
  const int wv = tid >> 6;
  size_t obase = (size_t)z * NWORDS + (size_t)r0*NWPR + (size_t)(c0 >> 6);
  for (int k = 0; k < 16; ++k) {
    int lr = wv + k*4;
    float m = mg[(lr+1)*MD + (lane+1)];
    int a = sax[lr*TA + lane];
    int dr = ((0x01 >> (2*a)) & 3) - 1;   // {0,-1,-1,-1}
    int dc = ((0x1A >> (2*a)) & 3) - 1;   // {1, 1, 0,-1}
    float m1 = mg[(lr+1+dr)*MD + (lane+1+dc)];
    float m2 = mg[(lr+1-dr)*MD + (lane+1-dc)];
    bool pass = (m > m1) && (m > m2);
    u64 sw = __ballot(pass && m > 0.039999f);   // (0.2^2 - eps)
    u64 wk = __ballot(pass && m > 0.009999f);   // (0.1^2 - eps)
    if (lane == 0) {
      strongw[obase + (size_t)lr*NWPR] = sw;
      weakw  [obase + (size_t)lr*NWPR] = wk;
    }
  }
}

// ---------------- Stage B: register-resident hysteresis + cross-dilate ----------------
// 512 threads = 8 waves; wave w owns rows 64w..64w+63 (lane = row within band).
// Each lane holds its full 512-bit row in 8 u64 registers. Vertical exchange via
// __shfl; band-boundary rows via LDS once per outer round.
__global__ __launch_bounds__(512) void k_hyst(const u64* __restrict__ strongw,
                                              const u64* __restrict__ weakw,
                                              u64* __restrict__ dil) {
  __shared__ u64 btop[8][8];   // wave w's row 64w
  __shared__ u64 bbot[8][8];   // wave w's row 64w+63
  __shared__ int gflag;
  const int z = blockIdx.x;
  const int tid = threadIdx.x;
  const int lane = tid & 63;
  const int w = tid >> 6;
  const int row = tid;

  const u64* sg = strongw + (size_t)z * NWORDS + (size_t)row * NWPR;
  const u64* wg = weakw   + (size_t)z * NWORDS + (size_t)row * NWPR;
  u64* dg = dil + (size_t)z * NWORDS + (size_t)row * NWPR;

  u64 S[8], W[8];
  #pragma unroll
  for (int cw = 0; cw < 8; ++cw) { S[cw] = sg[cw]; W[cw] = wg[cw]; }

  if (tid == 0) gflag = 0;
  if (lane == 0) {
    #pragma unroll
    for (int cw = 0; cw < 8; ++cw) btop[w][cw] = S[cw];
  }
  if (lane == 63) {
    #pragma unroll
    for (int cw = 0; cw < 8; ++cw) bbot[w][cw] = S[cw];
  }
  __syncthreads();

  for (int outer = 0; outer < 200; ++outer) {
    u64 up_b[8], dn_b[8];
    #pragma unroll
    for (int cw = 0; cw < 8; ++cw) {
      up_b[cw] = (w > 0) ? bbot[w-1][cw] : 0ull;
      dn_b[cw] = (w < 7) ? btop[w+1][cw] : 0ull;
    }
    int wchg = 0;
    for (int inner = 0; inner < 256; ++inner) {
      u64 v[8], changed = 0;
      #pragma unroll
      for (int cw = 0; cw < 8; ++cw) {
        u64 up = __shfl_up(S[cw], 1, 64);
        if (lane == 0) up = up_b[cw];
        u64 dn = __shfl_down(S[cw], 1, 64);
        if (lane == 63) dn = dn_b[cw];
        v[cw] = up | S[cw] | dn;
      }
      #pragma unroll
      for (int cw = 0; cw < 8; ++cw) {
        u64 vp = (cw > 0) ? v[cw-1] : 0ull;
        u64 vn = (cw < 7) ? v[cw+1] : 0ull;
        u64 D = (v[cw] << 1) | v[cw] | (v[cw] >> 1) | (vp >> 63) | (vn << 63);
        u64 ns = S[cw] | (W[cw] & D);
        changed |= ns ^ S[cw];
        S[cw] = ns;
      }
      if (!__any(changed != 0ull)) break;
      wchg = 1;
    }
    if (wchg && lane == 0) gflag = 1;
    __syncthreads();                    // all boundary reads + gflag writes done
    if (lane == 0) {
      #pragma unroll
      for (int cw = 0; cw < 8; ++cw) btop[w][cw] = S[cw];
    }
    if (lane == 63) {
      #pragma unroll
      for (int cw = 0; cw < 8; ++cw) bbot[w][cw] = S[cw];
    }
    int f = gflag;
    __syncthreads();                    // boundaries visible; gflag consumed
    if (tid == 0) gflag = 0;
    __syncthreads();
    if (!f) break;
  }

  // cross-dilate (center,up,down,left,right) and write out
  u64 d[8];
  #pragma unroll
  for (int cw = 0; cw < 8; ++cw) {
    u64 up = __shfl_up(S[cw], 1, 64);
    if (lane == 0) up = (w > 0) ? bbot[w-1][cw] : 0ull;
    u64 dn = __shfl_down(S[cw], 1, 64);
    if (lane == 63) dn = (w < 7) ? btop[w+1][cw] : 0ull;
    d[cw] = S[cw] | (S[cw] << 1) | (S[cw] >> 1) | up | dn;
  }
  #pragma unroll
  for (int cw = 0; cw < 8; ++cw) {
    if (cw > 0) d[cw] |= S[cw-1] >> 63;
    if (cw < 7) d[cw] |= S[cw+1] << 63;
  }
  #pragma unroll
  for (int cw = 0; cw < 8; cw += 2) {
    ulonglong2 v2; v2.x = d[cw]; v2.y = d[cw+1];
    *(ulonglong2*)&dg[cw] = v2;
  }
}

// ---------------- Stage C: loss reduction (4 pixels/thread) ----------------
__global__ __launch_bounds__(256) void k_loss(const float* __restrict__ pd,
                                              const int* __restrict__ gt,
                                              const float* __restrict__ wt,
                                              const u64* __restrict__ dil,
                                              double* __restrict__ acc) {
  int t = blockIdx.x * 256 + threadIdx.x;      // one thread = 4 consecutive pixels
  const int QP = NPIX / 4;
  int b = t / QP;
  int p = (t - b*QP) * 4;

  int4 g4 = *(const int4*)(gt + (size_t)b*NPIX + p);
  const float* pb = pd + (size_t)b * NC * NPIX + p;

  float m0=-3.4e38f,m1=-3.4e38f,m2=-3.4e38f,m3=-3.4e38f;
  float s0=0.f,s1=0.f,s2=0.f,s3=0.f;
  float v0=0.f,v1=0.f,v2=0.f,v3=0.f;
  #pragma unroll
  for (int c = 0; c < NC; ++c) {
    float4 x = *(const float4*)(pb + (size_t)c * NPIX);
    if (c == g4.x) v0 = x.x;
    if (c == g4.y) v1 = x.y;
    if (c == g4.z) v2 = x.z;
    if (c == g4.w) v3 = x.w;
    float n0 = fmaxf(m0, x.x); s0 = s0*expf(m0-n0) + expf(x.x-n0); m0 = n0;
    float n1 = fmaxf(m1, x.y); s1 = s1*expf(m1-n1) + expf(x.y-n1); m1 = n1;
    float n2 = fmaxf(m2, x.z); s2 = s2*expf(m2-n2) + expf(x.z-n2); m2 = n2;
    float n3 = fmaxf(m3, x.w); s3 = s3*expf(m3-n3) + expf(x.w-n3); m3 = n3;
  }
  const u64* db = dil + (size_t)b * NC * NWORDS;
  int wi = p >> 6, sh = p & 63;
  u64 w0 = db[(size_t)g4.x * NWORDS + wi];
  u64 w1 = db[(size_t)g4.y * NWORDS + wi];
  u64 w2 = db[(size_t)g4.z * NWORDS + wi];
  u64 w3 = db[(size_t)g4.w * NWORDS + wi];
  float e0 = (float)((w0 >> sh) & 1ull);
  float e1 = (float)((w1 >> (sh+1)) & 1ull);
  float e2 = (float)((w2 >> (sh+2)) & 1ull);
  float e3 = (float)((w3 >> (sh+3)) & 1ull);

  float contrib = wt[g4.x]*(v0 - (m0+logf(s0)))*(1.f+2.f*e0)
                + wt[g4.y]*(v1 - (m1+logf(s1)))*(1.f+2.f*e1)
                + wt[g4.z]*(v2 - (m2+logf(s2)))*(1.f+2.f*e2)
                + wt[g4.w]*(v3 - (m3+logf(s3)))*(1.f+2.f*e3);

  float sum = contrib;
  #pragma unroll
  for (int o = 32; o > 0; o >>= 1) sum += __shfl_down(sum, o, 64);
  __shared__ float wsum[4];
  if ((threadIdx.x & 63) == 0) wsum[threadIdx.x >> 6] = sum;
  __syncthreads();
  if (threadIdx.x == 0) {
    double d = (double)wsum[0] + (double)wsum[1] + (double)wsum[2] + (double)wsum[3];
    atomicAdd(acc, d);
  }
}

__global__ void k_fin(const double* __restrict__ acc, float* __restrict__ out) {
  if (threadIdx.x == 0 && blockIdx.x == 0)
    out[0] = (float)(-acc[0] / 2097152.0);
}

extern "C" void kernel_launch(void* const* d_in, const int* in_sizes, int n_in,
                              void* d_out, int out_size, void* d_ws, size_t ws_size,
                              hipStream_t stream) {
  const float* pd = (const float*)d_in[0];
  const int*   gt = (const int*)d_in[1];
  const float* wt = (const float*)d_in[2];
  float* out = (float*)d_out;

  double* acc = (double*)d_ws;
  u64* strongw = (u64*)((char*)d_ws + 256);
  u64* weakw   = strongw + (size_t)NB*NC*NWORDS;
  u64* dilw    = weakw   + (size_t)NB*NC*NWORDS;

  (void)hipMemsetAsync(d_ws, 0, 256, stream);

  dim3 gA(WW/TA, HH/TA, NB*NC);        // 8 x 8 x 88
  k_edges<<<gA, 256, 0, stream>>>(gt, strongw, weakw);

  k_hyst<<<NB*NC, 512, 0, stream>>>(strongw, weakw, dilw);

  k_loss<<<(NB*NPIX/4)/256, 256, 0, stream>>>(pd, gt, wt, dilw, acc);
  k_fin<<<1, 64, 0, stream>>>(acc, out);
}

// Round 5
// 138.124 us; speedup vs baseline: 5.7114x; 1.0771x over previous
//
#include <hip/hip_runtime.h>
#include <cstdint>
#include <cmath>

#define HH 512
#define WW 512
#define NB 8
#define NC 11
#define NPIX (HH*WW)
#define NWPR 8                 // 512/64 words per row
#define NWORDS (HH*NWPR)       // 4096 words per image-channel

typedef unsigned long long u64;
typedef uint32_t u32;

__device__ __forceinline__ int reflect512(int t) {
  t = t < 0 ? -t : t;
  return t > 511 ? 1022 - t : t;
}

// ---------------- Stage 0: bit-packed onehot planes ----------------
__global__ __launch_bounds__(256) void k_onehot(const int* __restrict__ gt,
                                                u64* __restrict__ planes) {
  int wave = (blockIdx.x * 256 + threadIdx.x) >> 6;   // 0..1023
  int lane = threadIdx.x & 63;
  for (int j = wave; j < NB*512*8; j += 1024) {
    int img = j >> 12;            // /4096
    int rw = j & 4095;            // row*8 + wg
    int gv = gt[(size_t)img*NPIX + rw*64 + lane];
    u64* base = planes + (size_t)img*NC*NWORDS + rw;
    #pragma unroll
    for (int c = 0; c < NC; ++c) {
      u64 m = __ballot(gv == c);
      if (lane == 0) base[(size_t)c*NWORDS] = m;
    }
  }
}

// ---------------- Stage A: blur+sobel+nms+threshold -> bitmasks ----------------
#define TA 64

__global__ __launch_bounds__(256) void k_edges(const u64* __restrict__ planes,
                                               u64* __restrict__ strongw,
                                               u64* __restrict__ weakw) {
  __shared__ u64 sbits[72][2];    // 1152 B : mask bits, row r = tile row r-4, bit b = tile col b-4
  __shared__ float sb[68*68];     // 18496 B: blurred, [lb][lbc] = tile (lb-2, lbc-2)
  __shared__ u32 su[68*72];       // 19584 B: t1 floats (68x72), then mag^2|axis u32 (66 rows x stride 68)

  const int z = blockIdx.z;          // bimg*NC + c
  const int r0 = blockIdx.y * TA, c0 = blockIdx.x * TA;
  const int tid = threadIdx.x;
  const u64* plane = planes + (size_t)z * NWORDS;

  // --- halo bit build: 72 rows, 2 words each (cols c0-4 .. c0+67 in bits 0..71) ---
  if (tid < 72) {
    int gr = reflect512(r0 + tid - 4);
    const u64* prow = plane + gr*8;
    int wi = c0 >> 6;
    u64 b = prow[wi];
    u64 w0, w1;
    if (c0 == 0) {
      u64 cc = prow[1];
      w0 = (b << 4) | ((__brevll(b) >> 59) & 0xFull);      // cols -4..-1 = reflect 4..1
      w1 = (b >> 60) | (cc << 4);
    } else if (c0 == WW - TA) {
      u64 a = prow[wi-1];
      w0 = (a >> 60) | (b << 4);
      w1 = (b >> 60) | (((__brevll(b) >> 1) & 0xFull) << 4); // cols 512..515 = reflect 510..507
    } else {
      u64 a = prow[wi-1];
      u64 cc = prow[wi+1];
      w0 = (a >> 60) | (b << 4);
      w1 = (b >> 60) | (cc << 4);
    }
    sbits[tid][0] = w0;
    sbits[tid][1] = w1;
  }
  __syncthreads();

  const float g0 = 0.054488684549642945f;
  const float g1 = 0.24420134200323332f;
  const float g2 = 0.4026199468942475f;

  // --- vertical blur: t1[68 rows][72 cols] floats; row r uses sbits rows r..r+4 ---
  float* t1f = (float*)su;
  for (int k = 0; k < 5; ++k) {
    int j = tid + 256*k;
    if (j < 68*18) {
      int row = j / 18;
      int grp = j - row*18;
      int widx = grp >> 4;
      int shift = (grp & 15) * 4;        // grp 16 -> widx1 shift0, grp 17 -> widx1 shift4 (grp&15 = 0,1)
      u32 sp[5];
      #pragma unroll
      for (int d = 0; d < 5; ++d) {
        u32 nib = (u32)(sbits[row+d][widx] >> shift) & 0xFu;
        sp[d] = (nib * 0x00204081u) & 0x01010101u;
      }
      u32 s04 = sp[0] + sp[4];
      u32 s13 = sp[1] + sp[3];
      u32 s2  = sp[2];
      float4 o;
      float* op = &o.x;
      #pragma unroll
      for (int jj = 0; jj < 4; ++jj) {
        float a  = (float)((s04 >> (8*jj)) & 0xffu);
        float bb = (float)((s13 >> (8*jj)) & 0xffu);
        float d  = (float)((s2  >> (8*jj)) & 0xffu);
        op[jj] = g0*a + g1*bb + g2*d;
      }
      *(float4*)&t1f[row*72 + grp*4] = o;
    }
  }
  __syncthreads();

  // --- horizontal blur: sb[lb][lbc] from t1 cols lbc..lbc+4 ---
  for (int k = 0; k < 5; ++k) {
    int q = tid + 256*k;
    if (q < 68*17) {
      int lb = q / 17, lcq = q - lb*17;
      const float* rp = &t1f[lb*72 + lcq*4];
      float4 a = *(const float4*)rp;
      float4 b = *(const float4*)(rp + 4);
      float4 o;
      o.x = g0*(a.x + b.x) + g1*(a.y + a.w) + g2*a.z;
      o.y = g0*(a.y + b.y) + g1*(a.z + b.x) + g2*a.w;
      o.z = g0*(a.z + b.z) + g1*(a.w + b.y) + g2*b.x;
      o.w = g0*(a.w + b.w) + g1*(b.x + b.z) + g2*b.y;
      *(float4*)&sb[lb*68 + lcq*4] = o;
    }
  }
  __syncthreads();

  // --- bake Sobel edge-clamp into sb (border blocks only) ---
  if (r0 == 0)      for (int i = tid; i < 2*68; i += 256) { int rr = i/68, cc = i - (i/68)*68; sb[rr*68 + cc] = sb[2*68 + cc]; }
  if (r0 == HH-TA)  for (int i = tid; i < 2*68; i += 256) { int rr = 66 + i/68, cc = i % 68;  sb[rr*68 + cc] = sb[65*68 + cc]; }
  __syncthreads();
  if (c0 == 0)      for (int i = tid; i < 2*68; i += 256) { int rr = i >> 1, cc = i & 1;       sb[rr*68 + cc] = sb[rr*68 + 2]; }
  if (c0 == WW-TA)  for (int i = tid; i < 2*68; i += 256) { int rr = i >> 1, cc = 66 + (i & 1); sb[rr*68 + cc] = sb[rr*68 + 65]; }
  __syncthreads();

  // --- sobel -> mag^2 with axis in low 2 bits (u32), stride 68; 4-col strips ---
  u32* mg = su;   // t1 dead
  for (int k = 0; k < 5; ++k) {
    int idx = tid + 256*k;
    if (idx < 66*16) {
      int row = idx >> 4;          // 0..65 (mag row)
      int g = idx & 15;
      int cbase = g*4;             // mag cols cbase..cbase+3 (0..63)
      const float* p0 = &sb[row*68 + cbase];
      float u[6], v[6];
      #pragma unroll
      for (int c = 0; c < 6; ++c) {
        float b0 = p0[c], b1 = p0[68+c], b2 = p0[136+c];
        u[c] = b0 + 2.f*b1 + b2;
        v[c] = b2 - b0;
      }
      int gm = r0 + row - 1;
      #pragma unroll
      for (int jj = 0; jj < 4; ++jj) {
        float gx = u[jj+2] - u[jj];
        float gy = v[jj] + 2.f*v[jj+1] + v[jj+2];
        float gx2 = gx*gx, gy2 = gy*gy;
        float mvf = gx2 + gy2;
        int axis;
        if (gy2 <= 0.17157287525f*gx2) axis = 0;
        else if (gy2 >= 5.82842712475f*gx2) axis = 2;
        else axis = (gx*gy > 0.f) ? 1 : 3;
        int gmc = c0 + cbase + jj - 1;
        u32 bits = (__float_as_uint(mvf) & ~3u) | (u32)axis;
        bool in = ((unsigned)gm < 512u) && ((unsigned)gmc < 512u);
        mg[row*68 + cbase + jj] = in ? bits : 0u;
      }
    }
  }
  // extra mag cols 64,65
  if (tid < 132) {
    int row = tid >> 1, col = 64 + (tid & 1);
    const float* p0 = &sb[row*68 + col];
    float b00=p0[0],   b01=p0[1],   b02=p0[2];
    float b10=p0[68],               b12=p0[70];
    float b20=p0[136], b21=p0[137], b22=p0[138];
    float gx = (b02 + 2.f*b12 + b22) - (b00 + 2.f*b10 + b20);
    float gy = (b20 + 2.f*b21 + b22) - (b00 + 2.f*b01 + b02);
    float gx2 = gx*gx, gy2 = gy*gy;
    float mvf = gx2 + gy2;
    int axis;
    if (gy2 <= 0.17157287525f*gx2) axis = 0;
    else if (gy2 >= 5.82842712475f*gx2) axis = 2;
    else axis = (gx*gy > 0.f) ? 1 : 3;
    int gm = r0 + row - 1, gmc = c0 + col - 1;
    u32 bits = (__float_as_uint(mvf) & ~3u) | (u32)axis;
    bool in = ((unsigned)gm < 512u) && ((unsigned)gmc < 512u);
    mg[row*68 + col] = in ? bits : 0u;
  }
  __syncthreads();

  // --- NMS + double threshold (u32 compares on masked bits) -> ballot words ---
  const int lane = tid & 63;
  const int wv = tid >> 6;
  const u32 THS = __float_as_uint(0.039999f);   // 0.2^2 - eps
  const u32 THW = __float_as_uint(0.009999f);   // 0.1^2 - eps
  size_t obase = (size_t)z * NWORDS + (size_t)r0*NWPR + (size_t)(c0 >> 6);
  for (int k = 0; k < 16; ++k) {
    int lr = wv + k*4;
    u32 mw = mg[(lr+1)*68 + (lane+1)];
    u32 m = mw & ~3u;
    int a = mw & 3;
    int dr = ((0x01 >> (2*a)) & 3) - 1;   // {0,-1,-1,-1}
    int dc = ((0x1A >> (2*a)) & 3) - 1;   // {1, 1, 0,-1}
    u32 m1 = mg[(lr+1+dr)*68 + (lane+1+dc)] & ~3u;
    u32 m2 = mg[(lr+1-dr)*68 + (lane+1-dc)] & ~3u;
    bool pass = (m > m1) && (m > m2);
    u64 sw = __ballot(pass && m > THS);
    u64 wk = __ballot(pass && m > THW);
    if (lane == 0) {
      strongw[obase + (size_t)lr*NWPR] = sw;
      weakw  [obase + (size_t)lr*NWPR] = wk;
    }
  }
}

// ---------------- Stage B: register-resident hysteresis + cross-dilate ----------------
__global__ __launch_bounds__(512) void k_hyst(const u64* __restrict__ strongw,
                                              const u64* __restrict__ weakw,
                                              u64* __restrict__ dil) {
  __shared__ u64 btop[8][8];
  __shared__ u64 bbot[8][8];
  __shared__ int gflag;
  const int z = blockIdx.x;
  const int tid = threadIdx.x;
  const int lane = tid & 63;
  const int w = tid >> 6;
  const int row = tid;

  const u64* sg = strongw + (size_t)z * NWORDS + (size_t)row * NWPR;
  const u64* wg = weakw   + (size_t)z * NWORDS + (size_t)row * NWPR;
  u64* dg = dil + (size_t)z * NWORDS + (size_t)row * NWPR;

  u64 S[8], W[8];
  #pragma unroll
  for (int cw = 0; cw < 8; ++cw) { S[cw] = sg[cw]; W[cw] = wg[cw]; }

  if (tid == 0) gflag = 0;
  if (lane == 0) {
    #pragma unroll
    for (int cw = 0; cw < 8; ++cw) btop[w][cw] = S[cw];
  }
  if (lane == 63) {
    #pragma unroll
    for (int cw = 0; cw < 8; ++cw) bbot[w][cw] = S[cw];
  }
  __syncthreads();

  for (int outer = 0; outer < 200; ++outer) {
    u64 up_b[8], dn_b[8];
    #pragma unroll
    for (int cw = 0; cw < 8; ++cw) {
      up_b[cw] = (w > 0) ? bbot[w-1][cw] : 0ull;
      dn_b[cw] = (w < 7) ? btop[w+1][cw] : 0ull;
    }
    int wchg = 0;
    for (int inner = 0; inner < 256; ++inner) {
      u64 v[8], changed = 0;
      #pragma unroll
      for (int cw = 0; cw < 8; ++cw) {
        u64 up = __shfl_up(S[cw], 1, 64);
        if (lane == 0) up = up_b[cw];
        u64 dn = __shfl_down(S[cw], 1, 64);
        if (lane == 63) dn = dn_b[cw];
        v[cw] = up | S[cw] | dn;
      }
      #pragma unroll
      for (int cw = 0; cw < 8; ++cw) {
        u64 vp = (cw > 0) ? v[cw-1] : 0ull;
        u64 vn = (cw < 7) ? v[cw+1] : 0ull;
        u64 D = (v[cw] << 1) | v[cw] | (v[cw] >> 1) | (vp >> 63) | (vn << 63);
        u64 ns = S[cw] | (W[cw] & D);
        changed |= ns ^ S[cw];
        S[cw] = ns;
      }
      if (!__any(changed != 0ull)) break;
      wchg = 1;
    }
    if (wchg && lane == 0) gflag = 1;
    __syncthreads();
    if (lane == 0) {
      #pragma unroll
      for (int cw = 0; cw < 8; ++cw) btop[w][cw] = S[cw];
    }
    if (lane == 63) {
      #pragma unroll
      for (int cw = 0; cw < 8; ++cw) bbot[w][cw] = S[cw];
    }
    int f = gflag;
    __syncthreads();
    if (tid == 0) gflag = 0;
    __syncthreads();
    if (!f) break;
  }

  u64 d[8];
  #pragma unroll
  for (int cw = 0; cw < 8; ++cw) {
    u64 up = __shfl_up(S[cw], 1, 64);
    if (lane == 0) up = (w > 0) ? bbot[w-1][cw] : 0ull;
    u64 dn = __shfl_down(S[cw], 1, 64);
    if (lane == 63) dn = (w < 7) ? btop[w+1][cw] : 0ull;
    d[cw] = S[cw] | (S[cw] << 1) | (S[cw] >> 1) | up | dn;
  }
  #pragma unroll
  for (int cw = 0; cw < 8; ++cw) {
    if (cw > 0) d[cw] |= S[cw-1] >> 63;
    if (cw < 7) d[cw] |= S[cw+1] << 63;
  }
  #pragma unroll
  for (int cw = 0; cw < 8; cw += 2) {
    ulonglong2 v2; v2.x = d[cw]; v2.y = d[cw+1];
    *(ulonglong2*)&dg[cw] = v2;
  }
}

// ---------------- Stage C: loss reduction (4 pixels/thread) ----------------
__global__ __launch_bounds__(256) void k_loss(const float* __restrict__ pd,
                                              const int* __restrict__ gt,
                                              const float* __restrict__ wt,
                                              const u64* __restrict__ dil,
                                              double* __restrict__ acc) {
  int t = blockIdx.x * 256 + threadIdx.x;
  const int QP = NPIX / 4;
  int b = t / QP;
  int p = (t - b*QP) * 4;

  int4 g4 = *(const int4*)(gt + (size_t)b*NPIX + p);
  const float* pb = pd + (size_t)b * NC * NPIX + p;

  float m0=-3.4e38f,m1=-3.4e38f,m2=-3.4e38f,m3=-3.4e38f;
  float s0=0.f,s1=0.f,s2=0.f,s3=0.f;
  float v0=0.f,v1=0.f,v2=0.f,v3=0.f;
  #pragma unroll
  for (int c = 0; c < NC; ++c) {
    float4 x = *(const float4*)(pb + (size_t)c * NPIX);
    if (c == g4.x) v0 = x.x;
    if (c == g4.y) v1 = x.y;
    if (c == g4.z) v2 = x.z;
    if (c == g4.w) v3 = x.w;
    float n0 = fmaxf(m0, x.x); s0 = s0*expf(m0-n0) + expf(x.x-n0); m0 = n0;
    float n1 = fmaxf(m1, x.y); s1 = s1*expf(m1-n1) + expf(x.y-n1); m1 = n1;
    float n2 = fmaxf(m2, x.z); s2 = s2*expf(m2-n2) + expf(x.z-n2); m2 = n2;
    float n3 = fmaxf(m3, x.w); s3 = s3*expf(m3-n3) + expf(x.w-n3); m3 = n3;
  }
  const u64* db = dil + (size_t)b * NC * NWORDS;
  int wi = p >> 6, sh = p & 63;
  u64 w0 = db[(size_t)g4.x * NWORDS + wi];
  u64 w1 = db[(size_t)g4.y * NWORDS + wi];
  u64 w2 = db[(size_t)g4.z * NWORDS + wi];
  u64 w3 = db[(size_t)g4.w * NWORDS + wi];
  float e0 = (float)((w0 >> sh) & 1ull);
  float e1 = (float)((w1 >> (sh+1)) & 1ull);
  float e2 = (float)((w2 >> (sh+2)) & 1ull);
  float e3 = (float)((w3 >> (sh+3)) & 1ull);

  float contrib = wt[g4.x]*(v0 - (m0+logf(s0)))*(1.f+2.f*e0)
                + wt[g4.y]*(v1 - (m1+logf(s1)))*(1.f+2.f*e1)
                + wt[g4.z]*(v2 - (m2+logf(s2)))*(1.f+2.f*e2)
                + wt[g4.w]*(v3 - (m3+logf(s3)))*(1.f+2.f*e3);

  float sum = contrib;
  #pragma unroll
  for (int o = 32; o > 0; o >>= 1) sum += __shfl_down(sum, o, 64);
  __shared__ float wsum[4];
  if ((threadIdx.x & 63) == 0) wsum[threadIdx.x >> 6] = sum;
  __syncthreads();
  if (threadIdx.x == 0) {
    double d = (double)wsum[0] + (double)wsum[1] + (double)wsum[2] + (double)wsum[3];
    atomicAdd(acc, d);
  }
}

__global__ void k_fin(const double* __restrict__ acc, float* __restrict__ out) {
  if (threadIdx.x == 0 && blockIdx.x == 0)
    out[0] = (float)(-acc[0] / 2097152.0);
}

extern "C" void kernel_launch(void* const* d_in, const int* in_sizes, int n_in,
                              void* d_out, int out_size, void* d_ws, size_t ws_size,
                              hipStream_t stream) {
  const float* pd = (const float*)d_in[0];
  const int*   gt = (const int*)d_in[1];
  const float* wt = (const float*)d_in[2];
  float* out = (float*)d_out;

  double* acc = (double*)d_ws;
  u64* strongw = (u64*)((char*)d_ws + 256);
  u64* weakw   = strongw + (size_t)NB*NC*NWORDS;
  u64* dilw    = weakw   + (size_t)NB*NC*NWORDS;
  u64* planes  = dilw;   // overlay: planes dead before dilw written

  (void)hipMemsetAsync(d_ws, 0, 256, stream);

  k_onehot<<<256, 256, 0, stream>>>(gt, planes);

  dim3 gA(WW/TA, HH/TA, NB*NC);        // 8 x 8 x 88
  k_edges<<<gA, 256, 0, stream>>>(planes, strongw, weakw);

  k_hyst<<<NB*NC, 512, 0, stream>>>(strongw, weakw, dilw);

  k_loss<<<(NB*NPIX/4)/256, 256, 0, stream>>>(pd, gt, wt, dilw, acc);
  k_fin<<<1, 64, 0, stream>>>(acc, out);
}

// Round 6
// 122.450 us; speedup vs baseline: 6.4424x; 1.1280x over previous
//
#include <hip/hip_runtime.h>
#include <cstdint>
#include <cmath>

#define HH 512
#define WW 512
#define NB 8
#define NC 11
#define NPIX (HH*WW)
#define NWPR 8                 // 512/64 words per row
#define NWORDS (HH*NWPR)       // 4096 words per image-channel

typedef unsigned long long u64;
typedef uint32_t u32;

__device__ __forceinline__ int reflect512(int t) {
  t = t < 0 ? -t : t;
  return t > 511 ? 1022 - t : t;
}

// ---------------- Stage 0: bit-packed onehot planes ----------------
__global__ __launch_bounds__(256) void k_onehot(const int* __restrict__ gt,
                                                u64* __restrict__ planes) {
  int wave = (blockIdx.x * 256 + threadIdx.x) >> 6;   // 0..4095
  int lane = threadIdx.x & 63;
  for (int j = wave; j < NB*512*8; j += 4096) {
    int img = j >> 12;            // /4096
    int rw = j & 4095;            // word index within image
    int gv = gt[(size_t)img*NPIX + rw*64 + lane];
    u64 my = 0;
    #pragma unroll
    for (int c = 0; c < NC; ++c) {
      u64 m = __ballot(gv == c);
      if (lane == c) my = m;
    }
    if (lane < NC)
      planes[(size_t)img*NC*NWORDS + (size_t)lane*NWORDS + rw] = my;
  }
}

// ---------------- Stage A: blur+sobel+nms+threshold -> bitmasks ----------------
#define TA 64

__global__ __launch_bounds__(256) void k_edges(const u64* __restrict__ planes,
                                               u64* __restrict__ strongw,
                                               u64* __restrict__ weakw) {
  __shared__ u64 sbits[72][2];    // 1152 B : mask bits, row r = tile row r-4, bit b = tile col b-4
  __shared__ float sb[68*68];     // 18496 B: blurred, [lb][lbc] = tile (lb-2, lbc-2)
  __shared__ u32 su[68*72];       // 19584 B: t1 floats (68x72), then mag^2|axis u32 (66 rows x stride 68)

  const int z = blockIdx.z;          // bimg*NC + c
  const int r0 = blockIdx.y * TA, c0 = blockIdx.x * TA;
  const int tid = threadIdx.x;
  const u64* plane = planes + (size_t)z * NWORDS;

  // --- halo bit build: 72 rows, 2 words each (cols c0-4 .. c0+67 in bits 0..71) ---
  if (tid < 72) {
    int gr = reflect512(r0 + tid - 4);
    const u64* prow = plane + gr*8;
    int wi = c0 >> 6;
    u64 b = prow[wi];
    u64 w0, w1;
    if (c0 == 0) {
      u64 cc = prow[1];
      w0 = (b << 4) | ((__brevll(b) >> 59) & 0xFull);      // cols -4..-1 = reflect 4..1
      w1 = (b >> 60) | (cc << 4);
    } else if (c0 == WW - TA) {
      u64 a = prow[wi-1];
      w0 = (a >> 60) | (b << 4);
      w1 = (b >> 60) | (((__brevll(b) >> 1) & 0xFull) << 4); // cols 512..515 = reflect 510..507
    } else {
      u64 a = prow[wi-1];
      u64 cc = prow[wi+1];
      w0 = (a >> 60) | (b << 4);
      w1 = (b >> 60) | (cc << 4);
    }
    sbits[tid][0] = w0;
    sbits[tid][1] = w1;
  }
  __syncthreads();

  const float g0 = 0.054488684549642945f;
  const float g1 = 0.24420134200323332f;
  const float g2 = 0.4026199468942475f;

  // --- vertical blur: t1[68 rows][72 cols] floats; row r uses sbits rows r..r+4 ---
  float* t1f = (float*)su;
  for (int k = 0; k < 5; ++k) {
    int j = tid + 256*k;
    if (j < 68*18) {
      int row = j / 18;
      int grp = j - row*18;
      int widx = grp >> 4;
      int shift = (grp & 15) * 4;
      u32 sp[5];
      #pragma unroll
      for (int d = 0; d < 5; ++d) {
        u32 nib = (u32)(sbits[row+d][widx] >> shift) & 0xFu;
        sp[d] = (nib * 0x00204081u) & 0x01010101u;
      }
      u32 s04 = sp[0] + sp[4];
      u32 s13 = sp[1] + sp[3];
      u32 s2  = sp[2];
      float4 o;
      float* op = &o.x;
      #pragma unroll
      for (int jj = 0; jj < 4; ++jj) {
        float a  = (float)((s04 >> (8*jj)) & 0xffu);
        float bb = (float)((s13 >> (8*jj)) & 0xffu);
        float d  = (float)((s2  >> (8*jj)) & 0xffu);
        op[jj] = g0*a + g1*bb + g2*d;
      }
      *(float4*)&t1f[row*72 + grp*4] = o;
    }
  }
  __syncthreads();

  // --- horizontal blur: sb[lb][lbc] from t1 cols lbc..lbc+4 ---
  for (int k = 0; k < 5; ++k) {
    int q = tid + 256*k;
    if (q < 68*17) {
      int lb = q / 17, lcq = q - lb*17;
      const float* rp = &t1f[lb*72 + lcq*4];
      float4 a = *(const float4*)rp;
      float4 b = *(const float4*)(rp + 4);
      float4 o;
      o.x = g0*(a.x + b.x) + g1*(a.y + a.w) + g2*a.z;
      o.y = g0*(a.y + b.y) + g1*(a.z + b.x) + g2*a.w;
      o.z = g0*(a.z + b.z) + g1*(a.w + b.y) + g2*b.x;
      o.w = g0*(a.w + b.w) + g1*(b.x + b.z) + g2*b.y;
      *(float4*)&sb[lb*68 + lcq*4] = o;
    }
  }
  __syncthreads();

  // --- bake Sobel edge-clamp into sb: single pass, fully-clamped source ---
  {
    const bool rb0 = (r0 == 0), rb1 = (r0 == HH-TA);
    const bool cb0 = (c0 == 0), cb1 = (c0 == WW-TA);
    if (rb0 | rb1 | cb0 | cb1) {
      for (int i = tid; i < 528; i += 256) {
        int rr, cc;
        if (i < 272) {                    // rows {0,1,66,67} x all cols
          int rI = i / 68;
          rr = (rI < 2) ? rI : 64 + rI;   // 0,1,66,67
          cc = i - rI*68;
        } else {                          // rows 2..65 x cols {0,1,66,67}
          int j = i - 272;
          rr = 2 + (j >> 2);
          int cI = j & 3;
          cc = (cI < 2) ? cI : 64 + cI;
        }
        int sr = (rb0 && rr < 2) ? 2 : ((rb1 && rr > 65) ? 65 : rr);
        int sc = (cb0 && cc < 2) ? 2 : ((cb1 && cc > 65) ? 65 : cc);
        if (sr != rr || sc != cc) sb[rr*68 + cc] = sb[sr*68 + sc];
      }
      __syncthreads();
    }
  }

  // --- sobel -> mag^2|axis (u32), stride 68; float4 LDS reads, uint4 store ---
  u32* mg = su;   // t1 dead
  for (int k = 0; k < 5; ++k) {
    int idx = tid + 256*k;
    if (idx < 66*16) {
      int row = idx >> 4;          // 0..65 (mag row)
      int g = idx & 15;
      int cbase = g*4;             // mag cols cbase..cbase+3
      const float* p0 = &sb[row*68 + cbase];
      float4 a0 = *(const float4*)(p0);
      float4 b0 = *(const float4*)(p0 + 4);
      float4 a1 = *(const float4*)(p0 + 68);
      float4 b1 = *(const float4*)(p0 + 72);
      float4 a2 = *(const float4*)(p0 + 136);
      float4 b2 = *(const float4*)(p0 + 140);
      float ur[6], vr[6];
      ur[0] = a0.x + 2.f*a1.x + a2.x;  vr[0] = a2.x - a0.x;
      ur[1] = a0.y + 2.f*a1.y + a2.y;  vr[1] = a2.y - a0.y;
      ur[2] = a0.z + 2.f*a1.z + a2.z;  vr[2] = a2.z - a0.z;
      ur[3] = a0.w + 2.f*a1.w + a2.w;  vr[3] = a2.w - a0.w;
      ur[4] = b0.x + 2.f*b1.x + b2.x;  vr[4] = b2.x - b0.x;
      ur[5] = b0.y + 2.f*b1.y + b2.y;  vr[5] = b2.y - b0.y;
      int gm = r0 + row - 1;
      uint4 ov;
      u32* ovp = &ov.x;
      #pragma unroll
      for (int jj = 0; jj < 4; ++jj) {
        float gx = ur[jj+2] - ur[jj];
        float gy = vr[jj] + 2.f*vr[jj+1] + vr[jj+2];
        float gx2 = gx*gx, gy2 = gy*gy;
        float mvf = gx2 + gy2;
        int axis;
        if (gy2 <= 0.17157287525f*gx2) axis = 0;
        else if (gy2 >= 5.82842712475f*gx2) axis = 2;
        else axis = (gx*gy > 0.f) ? 1 : 3;
        int gmc = c0 + cbase + jj - 1;
        u32 bits = (__float_as_uint(mvf) & ~3u) | (u32)axis;
        bool in = ((unsigned)gm < 512u) && ((unsigned)gmc < 512u);
        ovp[jj] = in ? bits : 0u;
      }
      *(uint4*)&mg[row*68 + cbase] = ov;
    }
  }
  // extra mag cols 64,65
  if (tid < 132) {
    int row = tid >> 1, col = 64 + (tid & 1);
    const float* p0 = &sb[row*68 + col];
    float b00=p0[0],   b01=p0[1],   b02=p0[2];
    float b10=p0[68],               b12=p0[70];
    float b20=p0[136], b21=p0[137], b22=p0[138];
    float gx = (b02 + 2.f*b12 + b22) - (b00 + 2.f*b10 + b20);
    float gy = (b20 + 2.f*b21 + b22) - (b00 + 2.f*b01 + b02);
    float gx2 = gx*gx, gy2 = gy*gy;
    float mvf = gx2 + gy2;
    int axis;
    if (gy2 <= 0.17157287525f*gx2) axis = 0;
    else if (gy2 >= 5.82842712475f*gx2) axis = 2;
    else axis = (gx*gy > 0.f) ? 1 : 3;
    int gm = r0 + row - 1, gmc = c0 + col - 1;
    u32 bits = (__float_as_uint(mvf) & ~3u) | (u32)axis;
    bool in = ((unsigned)gm < 512u) && ((unsigned)gmc < 512u);
    mg[row*68 + col] = in ? bits : 0u;
  }
  __syncthreads();

  // --- NMS + double threshold (u32 compares on masked bits) -> ballot words ---
  const int lane = tid & 63;
  const int wv = tid >> 6;
  const u32 THS = __float_as_uint(0.039999f);   // 0.2^2 - eps
  const u32 THW = __float_as_uint(0.009999f);   // 0.1^2 - eps
  size_t obase = (size_t)z * NWORDS + (size_t)r0*NWPR + (size_t)(c0 >> 6);
  for (int k = 0; k < 16; ++k) {
    int lr = wv + k*4;
    u32 mw = mg[(lr+1)*68 + (lane+1)];
    u32 m = mw & ~3u;
    int a = mw & 3;
    int dr = ((0x01 >> (2*a)) & 3) - 1;   // {0,-1,-1,-1}
    int dc = ((0x1A >> (2*a)) & 3) - 1;   // {1, 1, 0,-1}
    u32 m1 = mg[(lr+1+dr)*68 + (lane+1+dc)] & ~3u;
    u32 m2 = mg[(lr+1-dr)*68 + (lane+1-dc)] & ~3u;
    bool pass = (m > m1) && (m > m2);
    u64 sw = __ballot(pass && m > THS);
    u64 wk = __ballot(pass && m > THW);
    if (lane == 0) {
      strongw[obase + (size_t)lr*NWPR] = sw;
      weakw  [obase + (size_t)lr*NWPR] = wk;
    }
  }
}

// ---------------- Stage B: register-resident hysteresis + cross-dilate ----------------
__global__ __launch_bounds__(512) void k_hyst(const u64* __restrict__ strongw,
                                              const u64* __restrict__ weakw,
                                              u64* __restrict__ dil) {
  __shared__ u64 btop[8][8];
  __shared__ u64 bbot[8][8];
  __shared__ int gflag;
  const int z = blockIdx.x;
  const int tid = threadIdx.x;
  const int lane = tid & 63;
  const int w = tid >> 6;
  const int row = tid;

  const u64* sg = strongw + (size_t)z * NWORDS + (size_t)row * NWPR;
  const u64* wg = weakw   + (size_t)z * NWORDS + (size_t)row * NWPR;
  u64* dg = dil + (size_t)z * NWORDS + (size_t)row * NWPR;

  u64 S[8], W[8];
  #pragma unroll
  for (int cw = 0; cw < 8; ++cw) { S[cw] = sg[cw]; W[cw] = wg[cw]; }

  if (tid == 0) gflag = 0;
  if (lane == 0) {
    #pragma unroll
    for (int cw = 0; cw < 8; ++cw) btop[w][cw] = S[cw];
  }
  if (lane == 63) {
    #pragma unroll
    for (int cw = 0; cw < 8; ++cw) bbot[w][cw] = S[cw];
  }
  __syncthreads();

  for (int outer = 0; outer < 200; ++outer) {
    u64 up_b[8], dn_b[8];
    #pragma unroll
    for (int cw = 0; cw < 8; ++cw) {
      up_b[cw] = (w > 0) ? bbot[w-1][cw] : 0ull;
      dn_b[cw] = (w < 7) ? btop[w+1][cw] : 0ull;
    }
    int wchg = 0;
    for (int inner = 0; inner < 256; ++inner) {
      u64 v[8], changed = 0;
      #pragma unroll
      for (int cw = 0; cw < 8; ++cw) {
        u64 up = __shfl_up(S[cw], 1, 64);
        if (lane == 0) up = up_b[cw];
        u64 dn = __shfl_down(S[cw], 1, 64);
        if (lane == 63) dn = dn_b[cw];
        v[cw] = up | S[cw] | dn;
      }
      #pragma unroll
      for (int cw = 0; cw < 8; ++cw) {
        u64 vp = (cw > 0) ? v[cw-1] : 0ull;
        u64 vn = (cw < 7) ? v[cw+1] : 0ull;
        u64 D = (v[cw] << 1) | v[cw] | (v[cw] >> 1) | (vp >> 63) | (vn << 63);
        u64 ns = S[cw] | (W[cw] & D);
        changed |= ns ^ S[cw];
        S[cw] = ns;
      }
      if (!__any(changed != 0ull)) break;
      wchg = 1;
    }
    if (wchg && lane == 0) gflag = 1;
    __syncthreads();
    if (lane == 0) {
      #pragma unroll
      for (int cw = 0; cw < 8; ++cw) btop[w][cw] = S[cw];
    }
    if (lane == 63) {
      #pragma unroll
      for (int cw = 0; cw < 8; ++cw) bbot[w][cw] = S[cw];
    }
    int f = gflag;
    __syncthreads();
    if (tid == 0) gflag = 0;
    __syncthreads();
    if (!f) break;
  }

  u64 d[8];
  #pragma unroll
  for (int cw = 0; cw < 8; ++cw) {
    u64 up = __shfl_up(S[cw], 1, 64);
    if (lane == 0) up = (w > 0) ? bbot[w-1][cw] : 0ull;
    u64 dn = __shfl_down(S[cw], 1, 64);
    if (lane == 63) dn = (w < 7) ? btop[w+1][cw] : 0ull;
    d[cw] = S[cw] | (S[cw] << 1) | (S[cw] >> 1) | up | dn;
  }
  #pragma unroll
  for (int cw = 0; cw < 8; ++cw) {
    if (cw > 0) d[cw] |= S[cw-1] >> 63;
    if (cw < 7) d[cw] |= S[cw+1] << 63;
  }
  #pragma unroll
  for (int cw = 0; cw < 8; cw += 2) {
    ulonglong2 v2; v2.x = d[cw]; v2.y = d[cw+1];
    *(ulonglong2*)&dg[cw] = v2;
  }
}

// ---------------- Stage C: loss reduction (4 pixels/thread, direct exp-sum) ----------------
__global__ __launch_bounds__(256) void k_loss(const float* __restrict__ pd,
                                              const int* __restrict__ gt,
                                              const float* __restrict__ wt,
                                              const u64* __restrict__ dil,
                                              double* __restrict__ acc) {
  int t = blockIdx.x * 256 + threadIdx.x;
  const int QP = NPIX / 4;
  int b = t / QP;
  int p = (t - b*QP) * 4;

  int4 g4 = *(const int4*)(gt + (size_t)b*NPIX + p);
  const float* pb = pd + (size_t)b * NC * NPIX + p;

  float s0=0.f,s1=0.f,s2=0.f,s3=0.f;
  float v0=0.f,v1=0.f,v2=0.f,v3=0.f;
  #pragma unroll
  for (int c = 0; c < NC; ++c) {
    float4 x = *(const float4*)(pb + (size_t)c * NPIX);
    if (c == g4.x) v0 = x.x;
    if (c == g4.y) v1 = x.y;
    if (c == g4.z) v2 = x.z;
    if (c == g4.w) v3 = x.w;
    s0 += __expf(x.x);
    s1 += __expf(x.y);
    s2 += __expf(x.z);
    s3 += __expf(x.w);
  }
  const u64* db = dil + (size_t)b * NC * NWORDS;
  int wi = p >> 6, sh = p & 63;
  u64 w0 = db[(size_t)g4.x * NWORDS + wi];
  u64 w1 = db[(size_t)g4.y * NWORDS + wi];
  u64 w2 = db[(size_t)g4.z * NWORDS + wi];
  u64 w3 = db[(size_t)g4.w * NWORDS + wi];
  float e0 = (float)((w0 >> sh) & 1ull);
  float e1 = (float)((w1 >> (sh+1)) & 1ull);
  float e2 = (float)((w2 >> (sh+2)) & 1ull);
  float e3 = (float)((w3 >> (sh+3)) & 1ull);

  float contrib = wt[g4.x]*(v0 - __logf(s0))*(1.f+2.f*e0)
                + wt[g4.y]*(v1 - __logf(s1))*(1.f+2.f*e1)
                + wt[g4.z]*(v2 - __logf(s2))*(1.f+2.f*e2)
                + wt[g4.w]*(v3 - __logf(s3))*(1.f+2.f*e3);

  float sum = contrib;
  #pragma unroll
  for (int o = 32; o > 0; o >>= 1) sum += __shfl_down(sum, o, 64);
  __shared__ float wsum[4];
  if ((threadIdx.x & 63) == 0) wsum[threadIdx.x >> 6] = sum;
  __syncthreads();
  if (threadIdx.x == 0) {
    double d = (double)wsum[0] + (double)wsum[1] + (double)wsum[2] + (double)wsum[3];
    atomicAdd(acc, d);
  }
}

__global__ void k_fin(const double* __restrict__ acc, float* __restrict__ out) {
  if (threadIdx.x == 0 && blockIdx.x == 0)
    out[0] = (float)(-acc[0] / 2097152.0);
}

extern "C" void kernel_launch(void* const* d_in, const int* in_sizes, int n_in,
                              void* d_out, int out_size, void* d_ws, size_t ws_size,
                              hipStream_t stream) {
  const float* pd = (const float*)d_in[0];
  const int*   gt = (const int*)d_in[1];
  const float* wt = (const float*)d_in[2];
  float* out = (float*)d_out;

  double* acc = (double*)d_ws;
  u64* strongw = (u64*)((char*)d_ws + 256);
  u64* weakw   = strongw + (size_t)NB*NC*NWORDS;
  u64* dilw    = weakw   + (size_t)NB*NC*NWORDS;
  u64* planes  = dilw;   // overlay: planes dead before dilw written

  (void)hipMemsetAsync(d_ws, 0, 256, stream);

  k_onehot<<<1024, 256, 0, stream>>>(gt, planes);

  dim3 gA(WW/TA, HH/TA, NB*NC);        // 8 x 8 x 88
  k_edges<<<gA, 256, 0, stream>>>(planes, strongw, weakw);

  k_hyst<<<NB*NC, 512, 0, stream>>>(strongw, weakw, dilw);

  k_loss<<<(NB*NPIX/4)/256, 256, 0, stream>>>(pd, gt, wt, dilw, acc);
  k_fin<<<1, 64, 0, stream>>>(acc, out);
}